// Round 8
// baseline (218.074 us; speedup 1.0000x reference)
//
#include <hip/hip_runtime.h>
#include <math.h>

// NLM S=21, 256x256x3, reflect padding. Round 8: MFMA banded-matmul box sums.
// box = A2 (32x64 band) x f (64x64) x B1 (64x32 band), f16 MFMA 16x16x32, fp32 acc.
// Each wave owns its own offset stream -> NO barriers in the hot loop.
// Yloc = single-reflect fp16 luminance grid (double-reflect = per-row index calc).
// M1 relayout via per-wave private LDS strip (within-wave lgkmcnt ordering only).

#define IMG 256
#define NPIX (IMG * IMG)
#define TILE 32
#define YD 72        // staged Y rows/cols: [ti-20, ti+51]
#define PADL 6       // left pad in Yloc cols so y0 b128 reads are 16B-aligned
#define YSTR 88      // Yloc row stride in halves: 176B = 11*16 (aligned), 44 dwords -> 2-way banks
#define M1STR 72     // M1T row stride in halves: 144B = 9*16 (aligned), 36 dwords -> 2-way banks
#define CSTR 55      // Creg row stride in half4s (440B -> 2-way banks)
#define NOFF 441
#define NGB 12       // grid.y; 4 wave-streams each -> 48 offset streams

typedef _Float16 half8  __attribute__((ext_vector_type(8)));
typedef _Float16 half4t __attribute__((ext_vector_type(4)));
typedef float    float4t __attribute__((ext_vector_type(4)));

__device__ __forceinline__ int refl(int t) {
    t = t < 0 ? -t : t;             // valid for t in [-255, 510]
    return t > 255 ? 510 - t : t;
}

template <bool DIRECT>
__global__ __launch_bounds__(256, 3)
void nlm_main(const float* __restrict__ rgb, const float* __restrict__ hptr,
              float4* __restrict__ partials)
{
    // All reachable LDS is fully initialized (finite) -> band zeros kill garbage safely.
    __shared__ __align__(16) _Float16 Yloc[YD][YSTR];       // 12672 B
    __shared__ __align__(16) _Float16 Creg[52][CSTR][4];    // 22880 B
    __shared__ __align__(16) _Float16 M1T[4][32][M1STR];    // 18432 B (per-wave strips)
    // total 53984 B -> 3 blocks/CU

    const int tid = threadIdx.x;
    const int tj = ((int)blockIdx.x & 7) * TILE;
    const int ti = ((int)blockIdx.x >> 3) * TILE;

    // ---- stage Yloc: single-reflect clipped luminance, fp16, zero side pads ----
    for (int idx = tid; idx < YD * YSTR; idx += 256) {
        int a = idx / YSTR, b = idx - a * YSTR;
        _Float16 v = (_Float16)0.f;
        if (b >= PADL && b < PADL + YD) {
            int g = refl(ti - 20 + a) * IMG + refl(tj - 20 + (b - PADL));
            float r  = fminf(fmaxf(rgb[g], 0.f), 1.f);
            float gg = fminf(fmaxf(rgb[NPIX + g], 0.f), 1.f);
            float bb = fminf(fmaxf(rgb[2 * NPIX + g], 0.f), 1.f);
            v = (_Float16)(0.299f * r + 0.587f * gg + 0.114f * bb);
        }
        Yloc[a][b] = v;
    }
    // ---- stage Creg: single-reflect UNclipped RGBX taps (cols clamped into pad) ----
    for (int idx = tid; idx < 52 * CSTR; idx += 256) {
        int t = idx / CSTR, b = idx - t * CSTR;
        int bb = min(b, 51);
        int g = refl(ti - 10 + t) * IMG + refl(tj - 10 + bb);
        half4t c;
        c[0] = (_Float16)rgb[g];
        c[1] = (_Float16)rgb[NPIX + g];
        c[2] = (_Float16)rgb[2 * NPIX + g];
        c[3] = (_Float16)0.f;
        *(half4t*)&Creg[t][b][0] = c;
    }
    // ---- zero M1T (so stray in-array overreads are finite) ----
    {
        unsigned int* mz = (unsigned int*)&M1T[0][0][0];
        for (int idx = tid; idx < 4 * 32 * M1STR / 2; idx += 256) mz[idx] = 0u;
    }
    __syncthreads();   // the ONLY barrier

    const int lane = tid & 63;
    const int wv   = tid >> 6;          // wave id 0..3
    const int l    = lane & 15;
    const int q    = lane >> 4;

    // ---- banded 0/1 fragments; A2 (A-layout) and B1 (B-layout) share the
    //      same lane predicate: elem(l_idx=l+16*t, k=8q+32ks+j) = [l_idx <= k <= l_idx+20]
    half8 Bandf[2][2];
    #pragma unroll
    for (int t = 0; t < 2; ++t)
        #pragma unroll
        for (int ks = 0; ks < 2; ++ks) {
            half8 bb;
            #pragma unroll
            for (int j = 0; j < 8; ++j) {
                int k = 8 * q + 32 * ks + j;
                int c = l + 16 * t;
                bb[j] = (_Float16)((k >= c && k <= c + 20) ? 1.f : 0.f);
            }
            Bandf[t][ks] = bb;
        }

    const float hv = fmaxf(hptr[0], 0.f);
    const float negI = -1.0f / (hv + 1e-8f);

    float accR[16], accG[16], accB[16], accW[16];
    #pragma unroll
    for (int i = 0; i < 16; ++i) { accR[i]=0.f; accG[i]=0.f; accB[i]=0.f; accW[i]=0.f; }

    const int stream = (int)blockIdx.y * 4 + wv;   // 0..47

    for (int o = stream; o < NOFF; o += 48) {
        const int du = o / 21 - 10;
        const int dv = o % 21 - 10;

        // per-Mt row indices (double reflect for y1; proven in [0,71] for m<=51)
        int rm[4], r0[4];
        #pragma unroll
        for (int Mt = 0; Mt < 4; ++Mt) {
            int m = l + 16 * Mt;
            r0[Mt] = min(m, 51) + 10;
            int t1 = refl(ti - 10 + m);
            int t2 = refl(t1 + du);
            rm[Mt] = min(max(t2 - (ti - 20), 0), YD - 1);
        }
        // column vector-path flags (wave-uniform)
        bool cv[2];
        #pragma unroll
        for (int ks = 0; ks < 2; ++ks) {
            int kmin = 32 * ks, kmax = min(32 * ks + 31, 51);
            int lo = tj - 10 + kmin, hi = tj - 10 + kmax;
            cv[ks] = (lo >= 0) && (hi <= 255) && (lo + dv >= 0) && (hi + dv <= 255);
        }

        // ---- mfma1: M1 = f * B1 ----
        float4t D1[4][2];
        #pragma unroll
        for (int Mt = 0; Mt < 4; ++Mt) { D1[Mt][0] = (float4t)0.f; D1[Mt][1] = (float4t)0.f; }

        #pragma unroll
        for (int Mt = 0; Mt < 4; ++Mt) {
            #pragma unroll
            for (int ks = 0; ks < 2; ++ks) {
                const int K0 = 32 * ks + 8 * q;
                half8 y0v = *(const half8*)&Yloc[r0[Mt]][K0 + 10 + PADL];
                half8 y1v;
                if (cv[ks]) {
                    const int base_h = K0 + dv + 10 + PADL;
                    const int ab = base_h & ~3;
                    const int sh = base_h & 3;          // wave-uniform (= (dv+16)&3)
                    const unsigned int* dp = (const unsigned int*)&Yloc[rm[Mt]][ab];
                    unsigned int dd[6];
                    #pragma unroll
                    for (int i = 0; i < 6; ++i) dd[i] = dp[i];
                    unsigned int e0, e1, e2, e3, e4;
                    if (sh >> 1) { e0=dd[1]; e1=dd[2]; e2=dd[3]; e3=dd[4]; e4=dd[5]; }
                    else         { e0=dd[0]; e1=dd[1]; e2=dd[2]; e3=dd[3]; e4=dd[4]; }
                    union { unsigned int u[4]; half8 h; } uu;
                    if (sh & 1) {
                        uu.u[0] = (e0 >> 16) | (e1 << 16);
                        uu.u[1] = (e1 >> 16) | (e2 << 16);
                        uu.u[2] = (e2 >> 16) | (e3 << 16);
                        uu.u[3] = (e3 >> 16) | (e4 << 16);
                    } else {
                        uu.u[0] = e0; uu.u[1] = e1; uu.u[2] = e2; uu.u[3] = e3;
                    }
                    y1v = uu.h;
                } else {
                    #pragma unroll
                    for (int j = 0; j < 8; ++j) {
                        int k = K0 + j;
                        int c1 = refl(tj - 10 + k);
                        int c2 = refl(c1 + dv);
                        int cc = min(max(c2 - (tj - 20), 0), 81);
                        y1v[j] = Yloc[rm[Mt]][cc + PADL];
                    }
                }
                half8 df = y0v - y1v;
                half8 ff = df * df;
                D1[Mt][0] = __builtin_amdgcn_mfma_f32_16x16x32_f16(ff, Bandf[0][ks], D1[Mt][0], 0, 0, 0);
                D1[Mt][1] = __builtin_amdgcn_mfma_f32_16x16x32_f16(ff, Bandf[1][ks], D1[Mt][1], 0, 0, 0);
            }
            // relayout: D1 (row = 4q+reg + 16Mt, col = l + 16Nt) -> M1T[col][row], fp16
            #pragma unroll
            for (int Nt = 0; Nt < 2; ++Nt) {
                float4t d = D1[Mt][Nt];
                half4t pk;
                pk[0] = (_Float16)d[0]; pk[1] = (_Float16)d[1];
                pk[2] = (_Float16)d[2]; pk[3] = (_Float16)d[3];
                *(half4t*)&M1T[wv][l + 16 * Nt][16 * Mt + 4 * q] = pk;
            }
        }

        // ---- mfma2: box = A2 * M1 ----
        float4t D2[2][2];
        D2[0][0] = (float4t)0.f; D2[0][1] = (float4t)0.f;
        D2[1][0] = (float4t)0.f; D2[1][1] = (float4t)0.f;
        #pragma unroll
        for (int ks2 = 0; ks2 < 2; ++ks2) {
            half8 B2a = *(const half8*)&M1T[wv][l][8 * q + 32 * ks2];
            half8 B2b = *(const half8*)&M1T[wv][l + 16][8 * q + 32 * ks2];
            D2[0][0] = __builtin_amdgcn_mfma_f32_16x16x32_f16(Bandf[0][ks2], B2a, D2[0][0], 0, 0, 0);
            D2[0][1] = __builtin_amdgcn_mfma_f32_16x16x32_f16(Bandf[0][ks2], B2b, D2[0][1], 0, 0, 0);
            D2[1][0] = __builtin_amdgcn_mfma_f32_16x16x32_f16(Bandf[1][ks2], B2a, D2[1][0], 0, 0, 0);
            D2[1][1] = __builtin_amdgcn_mfma_f32_16x16x32_f16(Bandf[1][ks2], B2b, D2[1][1], 0, 0, 0);
        }

        // ---- epilogue: weight + accumulate (16 px/lane) ----
        #pragma unroll
        for (int Mt2 = 0; Mt2 < 2; ++Mt2)
            #pragma unroll
            for (int Nt2 = 0; Nt2 < 2; ++Nt2)
                #pragma unroll
                for (int rg = 0; rg < 4; ++rg) {
                    int p = 16 * Mt2 + 4 * q + rg;
                    int c = 16 * Nt2 + l;
                    float box = D2[Mt2][Nt2][rg];
                    float dist = sqrtf(fmaxf(box, 0.f));
                    float wgt = __expf(dist * negI);
                    half4t tap = *(const half4t*)&Creg[p + du + 10][c + dv + 10][0];
                    int idx = (Mt2 * 2 + Nt2) * 4 + rg;
                    accW[idx] += wgt;
                    accR[idx] += wgt * (float)tap[0];
                    accG[idx] += wgt * (float)tap[1];
                    accB[idx] += wgt * (float)tap[2];
                }
    }

    // ---- store partials ----
    #pragma unroll
    for (int Mt2 = 0; Mt2 < 2; ++Mt2)
        #pragma unroll
        for (int Nt2 = 0; Nt2 < 2; ++Nt2)
            #pragma unroll
            for (int rg = 0; rg < 4; ++rg) {
                int p = 16 * Mt2 + 4 * q + rg;
                int c = 16 * Nt2 + l;
                int gpix = (ti + p) * IMG + (tj + c);
                int idx = (Mt2 * 2 + Nt2) * 4 + rg;
                if (DIRECT) {
                    partials[(size_t)stream * NPIX + gpix] =
                        make_float4(accR[idx], accG[idx], accB[idx], accW[idx]);
                } else {
                    float* pp = (float*)&partials[(size_t)blockIdx.y * NPIX + gpix];
                    atomicAdd(pp + 0, accR[idx]);
                    atomicAdd(pp + 1, accG[idx]);
                    atomicAdd(pp + 2, accB[idx]);
                    atomicAdd(pp + 3, accW[idx]);
                }
            }
}

template <int NGT>
__global__ __launch_bounds__(256)
void nlm_finalize(const float4* __restrict__ partials, float* __restrict__ out)
{
    int idx = blockIdx.x * blockDim.x + threadIdx.x;
    float r = 0.f, g = 0.f, b = 0.f, w = 0.f;
    #pragma unroll
    for (int gg = 0; gg < NGT; ++gg) {
        float4 p = partials[(size_t)gg * NPIX + idx];
        r += p.x; g += p.y; b += p.z; w += p.w;
    }
    float inv = 1.0f / w;   // sum(w) >= 1 (self offset contributes exp(0))
    out[idx]            = fminf(fmaxf(r * inv, 0.f), 1.f);
    out[NPIX + idx]     = fminf(fmaxf(g * inv, 0.f), 1.f);
    out[2 * NPIX + idx] = fminf(fmaxf(b * inv, 0.f), 1.f);
}

extern "C" void kernel_launch(void* const* d_in, const int* in_sizes, int n_in,
                              void* d_out, int out_size, void* d_ws, size_t ws_size,
                              hipStream_t stream) {
    (void)in_sizes; (void)n_in; (void)out_size;
    const float* rgb  = (const float*)d_in[0];
    const float* hptr = (const float*)d_in[1];
    float* out = (float*)d_out;
    float4* partials = (float4*)d_ws;

    dim3 grid(64, NGB);   // 768 blocks = exactly 3 blocks/CU
    if (ws_size >= (size_t)48 * NPIX * sizeof(float4)) {          // 50.3 MB
        nlm_main<true><<<grid, 256, 0, stream>>>(rgb, hptr, partials);
        nlm_finalize<48><<<NPIX / 256, 256, 0, stream>>>(partials, out);
    } else {                                                       // >=16.8 MB proven
        (void)hipMemsetAsync(partials, 0, (size_t)NGB * NPIX * sizeof(float4), stream);
        nlm_main<false><<<grid, 256, 0, stream>>>(rgb, hptr, partials);
        nlm_finalize<NGB><<<NPIX / 256, 256, 0, stream>>>(partials, out);
    }
}

// Round 9
// 143.281 us; speedup vs baseline: 1.5220x; 1.5220x over previous
//
#include <hip/hip_runtime.h>
#include <math.h>

// NLM S=21, 256x256x3, reflect padding. Round 9 = R6 champion + targeted DS cuts:
// - persistent y0 row in 26 VGPRs (offset-invariant -> no per-offset y0 LDS reads)
// - single-wave h rows: lane t owns full 52-wide row, 32 slide outputs
//   (wave0 -> offset A, wave1 -> offset B); f computed once per row
// - edge tiles: cjTab consumed as wave-uniform broadcast u32 + bfe
// - dual-offset rounds (1 barrier/offset), fp16 hs ping-pong, fdot2 v-phase,
//   NG=16, direct-store partials, unrolled finalize (all as R6)

#define IMG 256
#define NPIX (IMG * IMG)
#define TILE 32
#define GR 52      // window-grid dim
#define YD 72      // staged Y rows/cols
#define YSTR 78    // Yreg row stride in halves (39 dwords, odd -> full bank spread)
#define RSTR 54    // hs row stride in halves (27 dwords, odd -> full bank spread)
#define NOFF 441
#define NG 16

typedef __attribute__((ext_vector_type(4))) _Float16 half4;
typedef __attribute__((ext_vector_type(2))) _Float16 half2_t;

#if __has_builtin(__builtin_amdgcn_fdot2)
#define FDOT2(a, b, c) __builtin_amdgcn_fdot2((a), (b), (c), false)
#else
#define FDOT2(a, b, c) ((c) + (float)(a).x * (float)(b).x + (float)(a).y * (float)(b).y)
#endif

__device__ __forceinline__ int refl(int t) {
    t = t < 0 ? -t : t;             // valid for t in [-255, 510]
    return t > 255 ? 510 - t : t;
}

template <bool DIRECT>
__global__ __launch_bounds__(256, 4)
void nlm_main(const float* __restrict__ rgb, const float* __restrict__ hptr,
              float4* __restrict__ partials)
{
    __shared__ _Float16 Yreg[YD][YSTR];          // 11232 B (clipped luminance, fp16)
    __shared__ _Float16 Creg4[GR][GR][4];        // 21632 B (RGBX taps at window grid)
    __shared__ _Float16 hsAB[2][TILE][RSTR];     //  6912 B (h-sums, fp16, ping-pong)
    __shared__ unsigned char cjTab[21][GR];      //  1092 B (col refl maps per dv; [10]=identity)
    // total 40868 B -> 4 blocks/CU

    const int tid = threadIdx.x;
    const int tj = ((int)blockIdx.x & 7) * TILE;
    const int ti = ((int)blockIdx.x >> 3) * TILE;

    const int Ybi = min(max(ti - 20, 0), IMG - YD);
    const int Ybj = min(max(tj - 20, 0), IMG - YD);
    const bool interior = (ti >= 20) && (ti + 51 <= 255) && (tj >= 20) && (tj + 51 <= 255);

    // ---- stage Y (clipped luminance, fp16) ----
    for (int idx = tid; idx < YD * YD; idx += 256) {
        int a = idx / YD, b = idx - a * YD;
        int g = (Ybi + a) * IMG + (Ybj + b);
        float r  = fminf(fmaxf(rgb[g], 0.f), 1.f);
        float gg = fminf(fmaxf(rgb[NPIX + g], 0.f), 1.f);
        float bb = fminf(fmaxf(rgb[2 * NPIX + g], 0.f), 1.f);
        Yreg[a][b] = (_Float16)(0.299f * r + 0.587f * gg + 0.114f * bb);
    }
    // ---- stage RGBX taps at window-grid coords (UNclipped rgb) ----
    for (int idx = tid; idx < GR * GR; idx += 256) {
        int t = idx / GR, b = idx - t * GR;
        int g = refl(ti - 10 + t) * IMG + refl(tj - 10 + b);
        half4 c;
        c.x = (_Float16)rgb[g];
        c.y = (_Float16)rgb[NPIX + g];
        c.z = (_Float16)rgb[2 * NPIX + g];
        c.w = (_Float16)0.f;
        *(half4*)&Creg4[t][b][0] = c;
    }
    // ---- col refl maps for all dv (edge tiles) ----
    if (!interior) {
        for (int idx = tid; idx < 21 * GR; idx += 256) {
            int d = idx / GR, c = idx - d * GR;
            cjTab[d][c] = (unsigned char)(refl(refl(tj - 10 + c) + (d - 10)) - Ybj);
        }
    }
    __syncthreads();   // staging complete

    const int lane = tid & 63;
    const int hw   = tid >> 6;               // wave id
    const bool hactive = (lane < GR) && (hw < 2);

    // ---- persistent y0 row (offset-invariant), 26 half2 regs ----
    half2_t y0h[26];
    if (hactive) {
        if (interior) {
            const half2_t* q0 = (const half2_t*)&Yreg[lane + 10][10];  // even offset
            #pragma unroll
            for (int i = 0; i < 26; ++i) y0h[i] = q0[i];
        } else {
            const _Float16* Y0row = &Yreg[refl(ti - 10 + lane) - Ybi][0];
            const unsigned char* cj0 = &cjTab[10][0];
            #pragma unroll
            for (int i = 0; i < 26; ++i) {
                half2_t v;
                v.x = Y0row[cj0[2 * i]];
                v.y = Y0row[cj0[2 * i + 1]];
                y0h[i] = v;
            }
        }
    }

    const float hv = fmaxf(hptr[0], 0.f);
    const float negI = -1.0f / (hv + 1e-8f);

    // v decomposition (as R6)
    const int pb = tid & 31;
    const int s4 = (tid >> 5) << 2;
    float aR[4], aG[4], aB[4], aW[4];
    #pragma unroll
    for (int k = 0; k < 4; ++k) { aR[k] = 0.f; aG[k] = 0.f; aB[k] = 0.f; aW[k] = 0.f; }

    half2_t one; one.x = (_Float16)1.f; one.y = (_Float16)1.f;

    auto do_h = [&](int du, int dv, int buf) {
        const int t = lane;
        _Float16* hsb = &hsAB[buf][0][0];
        float fv[52];
        if (interior) {
            half2_t ff[26];
            if ((dv & 1) == 0) {
                const half2_t* q1 = (const half2_t*)&Yreg[t + 10 + du][10 + dv];
                #pragma unroll
                for (int i = 0; i < 26; ++i) {
                    half2_t d2 = y0h[i] - q1[i];
                    ff[i] = d2 * d2;
                }
            } else {
                const half2_t* q1 = (const half2_t*)&Yreg[t + 10 + du][10 + dv - 1];
                half2_t prev = q1[0];
                #pragma unroll
                for (int i = 0; i < 26; ++i) {
                    half2_t cur = q1[i + 1];
                    half2_t b; b.x = prev.y; b.y = cur.x;
                    half2_t d2 = y0h[i] - b;
                    ff[i] = d2 * d2;
                    prev = cur;
                }
            }
            #pragma unroll
            for (int j = 0; j < 52; ++j)
                fv[j] = (float)((j & 1) ? ff[j >> 1].y : ff[j >> 1].x);
        } else {
            const unsigned int* cw = (const unsigned int*)&cjTab[dv + 10][0];  // wave-uniform
            const _Float16* Y1row = &Yreg[refl(refl(ti - 10 + t) + du) - Ybi][0];
            #pragma unroll
            for (int j = 0; j < 52; ++j) {
                unsigned int cj = (cw[j >> 2] >> ((j & 3) * 8)) & 0xffu;
                float y0 = (float)((j & 1) ? y0h[j >> 1].y : y0h[j >> 1].x);
                float d = y0 - (float)Y1row[cj];
                fv[j] = d * d;
            }
        }
        float s = fv[0];
        #pragma unroll
        for (int j = 1; j < 21; ++j) s += fv[j];
        hsb[t] = (_Float16)s;                        // c = 0
        #pragma unroll
        for (int k = 1; k < 32; ++k) {
            s += fv[20 + k] - fv[k - 1];
            hsb[k * RSTR + t] = (_Float16)s;
        }
    };

    auto do_v = [&](int du, int dv, int buf) {
        const half2_t* col = (const half2_t*)&hsAB[buf][pb][s4];  // even -> 4B aligned

        half2_t v[12];
        #pragma unroll
        for (int i = 0; i < 12; ++i) v[i] = col[i];
        float vs = 0.f;
        #pragma unroll
        for (int i = 0; i < 10; ++i) vs = FDOT2(v[i], one, vs);
        vs += (float)v[10].x;

        float vss[4];
        vss[0] = vs;
        vss[1] = vss[0] + (float)v[10].y - (float)v[0].x;
        vss[2] = vss[1] + (float)v[11].x - (float)v[0].y;
        vss[3] = vss[2] + (float)v[11].y - (float)v[1].x;

        const int cr = 10 + du;
        const int cc = pb + 10 + dv;
        #pragma unroll
        for (int k = 0; k < 4; ++k) {
            float dist = sqrtf(fmaxf(vss[k], 0.f));
            float w = __expf(dist * negI);
            half4 c = *(const half4*)&Creg4[s4 + k + cr][cc][0];
            aW[k] += w;
            aR[k] += w * (float)c.x;
            aG[k] += w * (float)c.y;
            aB[k] += w * (float)c.z;
        }
    };

    int duA = -10, dvA = (int)blockIdx.y - 10;

    for (int oA = (int)blockIdx.y; oA < NOFF; oA += 2 * NG) {
        int duB = duA, dvB = dvA + NG;
        if (dvB > 10) { dvB -= 21; duB += 1; }
        const bool hasB = (oA + NG) < NOFF;

        __syncthreads();   // hs buffers free (prev round's v done)

        if (hactive && (hasB || hw == 0))
            do_h(hw ? duB : duA, hw ? dvB : dvA, hw);

        __syncthreads();   // hs visible

        do_v(duA, dvA, 0);
        if (hasB) do_v(duB, dvB, 1);

        // advance A by 32 offsets (two wraps of 16)
        duA = duB; dvA = dvB + NG;
        if (dvA > 10) { dvA -= 21; duA += 1; }
    }

    // ---- epilogue: one float4 per pixel ----
    #pragma unroll
    for (int k = 0; k < 4; ++k) {
        int gpix = (ti + s4 + k) * IMG + (tj + pb);
        float4 st = make_float4(aR[k], aG[k], aB[k], aW[k]);
        if (DIRECT) {
            partials[(size_t)blockIdx.y * NPIX + gpix] = st;
        } else {
            float* p = (float*)&partials[gpix];
            atomicAdd(p + 0, st.x);
            atomicAdd(p + 1, st.y);
            atomicAdd(p + 2, st.z);
            atomicAdd(p + 3, st.w);
        }
    }
}

template <int NGT>
__global__ __launch_bounds__(256)
void nlm_finalize(const float4* __restrict__ partials, float* __restrict__ out)
{
    int idx = blockIdx.x * blockDim.x + threadIdx.x;
    float r = 0.f, g = 0.f, b = 0.f, w = 0.f;
    #pragma unroll
    for (int gg = 0; gg < NGT; ++gg) {
        float4 p = partials[(size_t)gg * NPIX + idx];
        r += p.x; g += p.y; b += p.z; w += p.w;
    }
    float inv = 1.0f / w;   // sum(w) >= 1 (self offset contributes exp(0))
    out[idx]            = fminf(fmaxf(r * inv, 0.f), 1.f);
    out[NPIX + idx]     = fminf(fmaxf(g * inv, 0.f), 1.f);
    out[2 * NPIX + idx] = fminf(fmaxf(b * inv, 0.f), 1.f);
}

extern "C" void kernel_launch(void* const* d_in, const int* in_sizes, int n_in,
                              void* d_out, int out_size, void* d_ws, size_t ws_size,
                              hipStream_t stream) {
    (void)in_sizes; (void)n_in; (void)out_size;
    const float* rgb  = (const float*)d_in[0];
    const float* hptr = (const float*)d_in[1];
    float* out = (float*)d_out;
    float4* partials = (float4*)d_ws;

    const bool direct = ws_size >= (size_t)NG * NPIX * sizeof(float4);  // 16.8 MB
    dim3 grid(64, NG);
    if (direct) {
        nlm_main<true><<<grid, 256, 0, stream>>>(rgb, hptr, partials);
        nlm_finalize<NG><<<NPIX / 256, 256, 0, stream>>>(partials, out);
    } else {
        (void)hipMemsetAsync(partials, 0, (size_t)NPIX * sizeof(float4), stream);
        nlm_main<false><<<grid, 256, 0, stream>>>(rgb, hptr, partials);
        nlm_finalize<1><<<NPIX / 256, 256, 0, stream>>>(partials, out);
    }
}

// Round 10
// 130.903 us; speedup vs baseline: 1.6659x; 1.0946x over previous
//
#include <hip/hip_runtime.h>
#include <math.h>

// NLM S=21, 256x256x3, reflect padding. Round 10 = R9 structure, spill fixed:
// - f-row kept as 26 packed half2 VGPRs (was float[52] -> scratch spill in R9)
// - slide extracts scalars on the fly (cvt_f32_f16 op_sel), init sum via fdot2
// - persistent y0 row in 13 VGPRs; single-wave h rows (wave0->A, wave1->B)
// - dual-offset rounds (1 barrier/offset), fp16 hs ping-pong, fdot2 v-phase,
//   NG=16, direct-store partials, unrolled finalize

#define IMG 256
#define NPIX (IMG * IMG)
#define TILE 32
#define GR 52      // window-grid dim
#define YD 72      // staged Y rows/cols
#define YSTR 78    // Yreg row stride in halves (39 dwords, odd -> full bank spread)
#define RSTR 54    // hs row stride in halves (27 dwords, odd -> full bank spread)
#define NOFF 441
#define NG 16

typedef __attribute__((ext_vector_type(4))) _Float16 half4;
typedef __attribute__((ext_vector_type(2))) _Float16 half2_t;

#if __has_builtin(__builtin_amdgcn_fdot2)
#define FDOT2(a, b, c) __builtin_amdgcn_fdot2((a), (b), (c), false)
#else
#define FDOT2(a, b, c) ((c) + (float)(a).x * (float)(b).x + (float)(a).y * (float)(b).y)
#endif

__device__ __forceinline__ int refl(int t) {
    t = t < 0 ? -t : t;             // valid for t in [-255, 510]
    return t > 255 ? 510 - t : t;
}

template <bool DIRECT>
__global__ __launch_bounds__(256, 4)
void nlm_main(const float* __restrict__ rgb, const float* __restrict__ hptr,
              float4* __restrict__ partials)
{
    __shared__ _Float16 Yreg[YD][YSTR];          // 11232 B (clipped luminance, fp16)
    __shared__ _Float16 Creg4[GR][GR][4];        // 21632 B (RGBX taps at window grid)
    __shared__ _Float16 hsAB[2][TILE][RSTR];     //  6912 B (h-sums, fp16, ping-pong)
    __shared__ unsigned char cjTab[21][GR];      //  1092 B (col refl maps per dv; [10]=identity)
    // total 40868 B -> 4 blocks/CU

    const int tid = threadIdx.x;
    const int tj = ((int)blockIdx.x & 7) * TILE;
    const int ti = ((int)blockIdx.x >> 3) * TILE;

    const int Ybi = min(max(ti - 20, 0), IMG - YD);
    const int Ybj = min(max(tj - 20, 0), IMG - YD);
    const bool interior = (ti >= 20) && (ti + 51 <= 255) && (tj >= 20) && (tj + 51 <= 255);

    // ---- stage Y (clipped luminance, fp16) ----
    for (int idx = tid; idx < YD * YD; idx += 256) {
        int a = idx / YD, b = idx - a * YD;
        int g = (Ybi + a) * IMG + (Ybj + b);
        float r  = fminf(fmaxf(rgb[g], 0.f), 1.f);
        float gg = fminf(fmaxf(rgb[NPIX + g], 0.f), 1.f);
        float bb = fminf(fmaxf(rgb[2 * NPIX + g], 0.f), 1.f);
        Yreg[a][b] = (_Float16)(0.299f * r + 0.587f * gg + 0.114f * bb);
    }
    // ---- stage RGBX taps at window-grid coords (UNclipped rgb) ----
    for (int idx = tid; idx < GR * GR; idx += 256) {
        int t = idx / GR, b = idx - t * GR;
        int g = refl(ti - 10 + t) * IMG + refl(tj - 10 + b);
        half4 c;
        c.x = (_Float16)rgb[g];
        c.y = (_Float16)rgb[NPIX + g];
        c.z = (_Float16)rgb[2 * NPIX + g];
        c.w = (_Float16)0.f;
        *(half4*)&Creg4[t][b][0] = c;
    }
    // ---- col refl maps for all dv (edge tiles) ----
    if (!interior) {
        for (int idx = tid; idx < 21 * GR; idx += 256) {
            int d = idx / GR, c = idx - d * GR;
            cjTab[d][c] = (unsigned char)(refl(refl(tj - 10 + c) + (d - 10)) - Ybj);
        }
    }
    __syncthreads();   // staging complete

    const int lane = tid & 63;
    const int hw   = tid >> 6;               // wave id
    const bool hactive = (lane < GR) && (hw < 2);

    // ---- persistent y0 row (offset-invariant), 26 half2 regs ----
    half2_t y0h[26];
    if (hactive) {
        if (interior) {
            const half2_t* q0 = (const half2_t*)&Yreg[lane + 10][10];  // even offset
            #pragma unroll
            for (int i = 0; i < 26; ++i) y0h[i] = q0[i];
        } else {
            const _Float16* Y0row = &Yreg[refl(ti - 10 + lane) - Ybi][0];
            const unsigned char* cj0 = &cjTab[10][0];
            #pragma unroll
            for (int i = 0; i < 26; ++i) {
                half2_t v;
                v.x = Y0row[cj0[2 * i]];
                v.y = Y0row[cj0[2 * i + 1]];
                y0h[i] = v;
            }
        }
    }

    const float hv = fmaxf(hptr[0], 0.f);
    const float negI = -1.0f / (hv + 1e-8f);

    // v decomposition
    const int pb = tid & 31;
    const int s4 = (tid >> 5) << 2;
    float aR[4], aG[4], aB[4], aW[4];
    #pragma unroll
    for (int k = 0; k < 4; ++k) { aR[k] = 0.f; aG[k] = 0.f; aB[k] = 0.f; aW[k] = 0.f; }

    half2_t one; one.x = (_Float16)1.f; one.y = (_Float16)1.f;

    auto do_h = [&](int du, int dv, int buf) {
        const int t = lane;
        _Float16* hsb = &hsAB[buf][0][0];
        half2_t ff[26];                       // packed f-row: 13 VGPRs, never spills
        if (interior) {
            if ((dv & 1) == 0) {
                const half2_t* q1 = (const half2_t*)&Yreg[t + 10 + du][10 + dv];
                #pragma unroll
                for (int i = 0; i < 26; ++i) {
                    half2_t d2 = y0h[i] - q1[i];
                    ff[i] = d2 * d2;
                }
            } else {
                const half2_t* q1 = (const half2_t*)&Yreg[t + 10 + du][10 + dv - 1];
                half2_t prev = q1[0];
                #pragma unroll
                for (int i = 0; i < 26; ++i) {
                    half2_t cur = q1[i + 1];
                    half2_t b; b.x = prev.y; b.y = cur.x;
                    half2_t d2 = y0h[i] - b;
                    ff[i] = d2 * d2;
                    prev = cur;
                }
            }
        } else {
            const unsigned int* cw = (const unsigned int*)&cjTab[dv + 10][0];  // wave-uniform
            const _Float16* Y1row = &Yreg[refl(refl(ti - 10 + t) + du) - Ybi][0];
            #pragma unroll
            for (int i = 0; i < 26; ++i) {
                unsigned int w0 = cw[i >> 1];
                int sh = (i & 1) * 16;
                _Float16 a0 = Y1row[(w0 >> sh) & 0xffu];
                _Float16 a1 = Y1row[(w0 >> (sh + 8)) & 0xffu];
                half2_t yv; yv.x = a0; yv.y = a1;
                half2_t d2 = y0h[i] - yv;
                ff[i] = d2 * d2;
            }
        }
        // initial sum f[0..20] = pairs ff[0..9] + ff[10].x
        float s = 0.f;
        #pragma unroll
        for (int i = 0; i < 10; ++i) s = FDOT2(ff[i], one, s);
        s += (float)ff[10].x;
        hsb[t] = (_Float16)s;                // c = 0
        // slide: s += f[20+k] - f[k-1], extract from packed on the fly
        #pragma unroll
        for (int k = 1; k < 32; ++k) {
            int ja = 20 + k, jb = k - 1;
            float fa = (float)((ja & 1) ? ff[ja >> 1].y : ff[ja >> 1].x);
            float fb = (float)((jb & 1) ? ff[jb >> 1].y : ff[jb >> 1].x);
            s += fa - fb;
            hsb[k * RSTR + t] = (_Float16)s;
        }
    };

    auto do_v = [&](int du, int dv, int buf) {
        const half2_t* col = (const half2_t*)&hsAB[buf][pb][s4];  // even -> 4B aligned

        half2_t v[12];
        #pragma unroll
        for (int i = 0; i < 12; ++i) v[i] = col[i];
        float vs = 0.f;
        #pragma unroll
        for (int i = 0; i < 10; ++i) vs = FDOT2(v[i], one, vs);
        vs += (float)v[10].x;

        float vss[4];
        vss[0] = vs;
        vss[1] = vss[0] + (float)v[10].y - (float)v[0].x;
        vss[2] = vss[1] + (float)v[11].x - (float)v[0].y;
        vss[3] = vss[2] + (float)v[11].y - (float)v[1].x;

        const int cr = 10 + du;
        const int cc = pb + 10 + dv;
        #pragma unroll
        for (int k = 0; k < 4; ++k) {
            float dist = sqrtf(fmaxf(vss[k], 0.f));
            float w = __expf(dist * negI);
            half4 c = *(const half4*)&Creg4[s4 + k + cr][cc][0];
            aW[k] += w;
            aR[k] += w * (float)c.x;
            aG[k] += w * (float)c.y;
            aB[k] += w * (float)c.z;
        }
    };

    int duA = -10, dvA = (int)blockIdx.y - 10;

    for (int oA = (int)blockIdx.y; oA < NOFF; oA += 2 * NG) {
        int duB = duA, dvB = dvA + NG;
        if (dvB > 10) { dvB -= 21; duB += 1; }
        const bool hasB = (oA + NG) < NOFF;

        __syncthreads();   // hs buffers free (prev round's v done)

        if (hactive && (hasB || hw == 0))
            do_h(hw ? duB : duA, hw ? dvB : dvA, hw);

        __syncthreads();   // hs visible

        do_v(duA, dvA, 0);
        if (hasB) do_v(duB, dvB, 1);

        // advance A by 32 offsets (two wraps of 16)
        duA = duB; dvA = dvB + NG;
        if (dvA > 10) { dvA -= 21; duA += 1; }
    }

    // ---- epilogue: one float4 per pixel ----
    #pragma unroll
    for (int k = 0; k < 4; ++k) {
        int gpix = (ti + s4 + k) * IMG + (tj + pb);
        float4 st = make_float4(aR[k], aG[k], aB[k], aW[k]);
        if (DIRECT) {
            partials[(size_t)blockIdx.y * NPIX + gpix] = st;
        } else {
            float* p = (float*)&partials[gpix];
            atomicAdd(p + 0, st.x);
            atomicAdd(p + 1, st.y);
            atomicAdd(p + 2, st.z);
            atomicAdd(p + 3, st.w);
        }
    }
}

template <int NGT>
__global__ __launch_bounds__(256)
void nlm_finalize(const float4* __restrict__ partials, float* __restrict__ out)
{
    int idx = blockIdx.x * blockDim.x + threadIdx.x;
    float r = 0.f, g = 0.f, b = 0.f, w = 0.f;
    #pragma unroll
    for (int gg = 0; gg < NGT; ++gg) {
        float4 p = partials[(size_t)gg * NPIX + idx];
        r += p.x; g += p.y; b += p.z; w += p.w;
    }
    float inv = 1.0f / w;   // sum(w) >= 1 (self offset contributes exp(0))
    out[idx]            = fminf(fmaxf(r * inv, 0.f), 1.f);
    out[NPIX + idx]     = fminf(fmaxf(g * inv, 0.f), 1.f);
    out[2 * NPIX + idx] = fminf(fmaxf(b * inv, 0.f), 1.f);
}

extern "C" void kernel_launch(void* const* d_in, const int* in_sizes, int n_in,
                              void* d_out, int out_size, void* d_ws, size_t ws_size,
                              hipStream_t stream) {
    (void)in_sizes; (void)n_in; (void)out_size;
    const float* rgb  = (const float*)d_in[0];
    const float* hptr = (const float*)d_in[1];
    float* out = (float*)d_out;
    float4* partials = (float4*)d_ws;

    const bool direct = ws_size >= (size_t)NG * NPIX * sizeof(float4);  // 16.8 MB
    dim3 grid(64, NG);
    if (direct) {
        nlm_main<true><<<grid, 256, 0, stream>>>(rgb, hptr, partials);
        nlm_finalize<NG><<<NPIX / 256, 256, 0, stream>>>(partials, out);
    } else {
        (void)hipMemsetAsync(partials, 0, (size_t)NPIX * sizeof(float4), stream);
        nlm_main<false><<<grid, 256, 0, stream>>>(rgb, hptr, partials);
        nlm_finalize<1><<<NPIX / 256, 256, 0, stream>>>(partials, out);
    }
}

// Round 11
// 124.822 us; speedup vs baseline: 1.7471x; 1.0487x over previous
//
#include <hip/hip_runtime.h>
#include <math.h>

// NLM S=21, 256x256x3, reflect padding. Round 11 = R10 + fp16 slide chains:
// - h-slide: scalar fp16 running sum (v_sub_f16/v_add_f16 with op_sel extracts,
//   no per-step f32 cvts; init sum exact via f32 fdot2) -> ~125 fewer VALU/offset
// - v-slide: fp16 diffs, f32 accumulate
// - persistent y0 row (13 VGPRs), packed half2 f-row (13 VGPRs, no spill)
// - dual-offset rounds (1 barrier/offset), fp16 hs ping-pong, fdot2 v-phase,
//   NG=16, direct-store partials, unrolled finalize

#define IMG 256
#define NPIX (IMG * IMG)
#define TILE 32
#define GR 52      // window-grid dim
#define YD 72      // staged Y rows/cols
#define YSTR 78    // Yreg row stride in halves (39 dwords, odd -> full bank spread)
#define RSTR 54    // hs row stride in halves (27 dwords, odd -> full bank spread)
#define NOFF 441
#define NG 16

typedef __attribute__((ext_vector_type(4))) _Float16 half4;
typedef __attribute__((ext_vector_type(2))) _Float16 half2_t;

#if __has_builtin(__builtin_amdgcn_fdot2)
#define FDOT2(a, b, c) __builtin_amdgcn_fdot2((a), (b), (c), false)
#else
#define FDOT2(a, b, c) ((c) + (float)(a).x * (float)(b).x + (float)(a).y * (float)(b).y)
#endif

__device__ __forceinline__ int refl(int t) {
    t = t < 0 ? -t : t;             // valid for t in [-255, 510]
    return t > 255 ? 510 - t : t;
}

template <bool DIRECT>
__global__ __launch_bounds__(256, 4)
void nlm_main(const float* __restrict__ rgb, const float* __restrict__ hptr,
              float4* __restrict__ partials)
{
    __shared__ _Float16 Yreg[YD][YSTR];          // 11232 B (clipped luminance, fp16)
    __shared__ _Float16 Creg4[GR][GR][4];        // 21632 B (RGBX taps at window grid)
    __shared__ _Float16 hsAB[2][TILE][RSTR];     //  6912 B (h-sums, fp16, ping-pong)
    __shared__ unsigned char cjTab[21][GR];      //  1092 B (col refl maps per dv; [10]=identity)
    // total 40868 B -> 4 blocks/CU

    const int tid = threadIdx.x;
    const int tj = ((int)blockIdx.x & 7) * TILE;
    const int ti = ((int)blockIdx.x >> 3) * TILE;

    const int Ybi = min(max(ti - 20, 0), IMG - YD);
    const int Ybj = min(max(tj - 20, 0), IMG - YD);
    const bool interior = (ti >= 20) && (ti + 51 <= 255) && (tj >= 20) && (tj + 51 <= 255);

    // ---- stage Y (clipped luminance, fp16) ----
    for (int idx = tid; idx < YD * YD; idx += 256) {
        int a = idx / YD, b = idx - a * YD;
        int g = (Ybi + a) * IMG + (Ybj + b);
        float r  = fminf(fmaxf(rgb[g], 0.f), 1.f);
        float gg = fminf(fmaxf(rgb[NPIX + g], 0.f), 1.f);
        float bb = fminf(fmaxf(rgb[2 * NPIX + g], 0.f), 1.f);
        Yreg[a][b] = (_Float16)(0.299f * r + 0.587f * gg + 0.114f * bb);
    }
    // ---- stage RGBX taps at window-grid coords (UNclipped rgb) ----
    for (int idx = tid; idx < GR * GR; idx += 256) {
        int t = idx / GR, b = idx - t * GR;
        int g = refl(ti - 10 + t) * IMG + refl(tj - 10 + b);
        half4 c;
        c.x = (_Float16)rgb[g];
        c.y = (_Float16)rgb[NPIX + g];
        c.z = (_Float16)rgb[2 * NPIX + g];
        c.w = (_Float16)0.f;
        *(half4*)&Creg4[t][b][0] = c;
    }
    // ---- col refl maps for all dv (edge tiles) ----
    if (!interior) {
        for (int idx = tid; idx < 21 * GR; idx += 256) {
            int d = idx / GR, c = idx - d * GR;
            cjTab[d][c] = (unsigned char)(refl(refl(tj - 10 + c) + (d - 10)) - Ybj);
        }
    }
    __syncthreads();   // staging complete

    const int lane = tid & 63;
    const int hw   = tid >> 6;               // wave id
    const bool hactive = (lane < GR) && (hw < 2);

    // ---- persistent y0 row (offset-invariant), 26 half2 regs ----
    half2_t y0h[26];
    if (hactive) {
        if (interior) {
            const half2_t* q0 = (const half2_t*)&Yreg[lane + 10][10];  // even offset
            #pragma unroll
            for (int i = 0; i < 26; ++i) y0h[i] = q0[i];
        } else {
            const _Float16* Y0row = &Yreg[refl(ti - 10 + lane) - Ybi][0];
            const unsigned char* cj0 = &cjTab[10][0];
            #pragma unroll
            for (int i = 0; i < 26; ++i) {
                half2_t v;
                v.x = Y0row[cj0[2 * i]];
                v.y = Y0row[cj0[2 * i + 1]];
                y0h[i] = v;
            }
        }
    }

    const float hv = fmaxf(hptr[0], 0.f);
    const float negI = -1.0f / (hv + 1e-8f);

    // v decomposition
    const int pb = tid & 31;
    const int s4 = (tid >> 5) << 2;
    float aR[4], aG[4], aB[4], aW[4];
    #pragma unroll
    for (int k = 0; k < 4; ++k) { aR[k] = 0.f; aG[k] = 0.f; aB[k] = 0.f; aW[k] = 0.f; }

    half2_t one; one.x = (_Float16)1.f; one.y = (_Float16)1.f;

    auto do_h = [&](int du, int dv, int buf) {
        const int t = lane;
        _Float16* hsb = &hsAB[buf][0][0];
        half2_t ff[26];                       // packed f-row: 13 VGPRs, never spills
        if (interior) {
            if ((dv & 1) == 0) {
                const half2_t* q1 = (const half2_t*)&Yreg[t + 10 + du][10 + dv];
                #pragma unroll
                for (int i = 0; i < 26; ++i) {
                    half2_t d2 = y0h[i] - q1[i];
                    ff[i] = d2 * d2;
                }
            } else {
                const half2_t* q1 = (const half2_t*)&Yreg[t + 10 + du][10 + dv - 1];
                half2_t prev = q1[0];
                #pragma unroll
                for (int i = 0; i < 26; ++i) {
                    half2_t cur = q1[i + 1];
                    half2_t b; b.x = prev.y; b.y = cur.x;
                    half2_t d2 = y0h[i] - b;
                    ff[i] = d2 * d2;
                    prev = cur;
                }
            }
        } else {
            const unsigned int* cw = (const unsigned int*)&cjTab[dv + 10][0];  // wave-uniform
            const _Float16* Y1row = &Yreg[refl(refl(ti - 10 + t) + du) - Ybi][0];
            #pragma unroll
            for (int i = 0; i < 26; ++i) {
                unsigned int w0 = cw[i >> 1];
                int sh = (i & 1) * 16;
                _Float16 a0 = Y1row[(w0 >> sh) & 0xffu];
                _Float16 a1 = Y1row[(w0 >> (sh + 8)) & 0xffu];
                half2_t yv; yv.x = a0; yv.y = a1;
                half2_t d2 = y0h[i] - yv;
                ff[i] = d2 * d2;
            }
        }
        // initial sum f[0..20] exact in f32 (pairs ff[0..9] + ff[10].x)
        float s0f = 0.f;
        #pragma unroll
        for (int i = 0; i < 10; ++i) s0f = FDOT2(ff[i], one, s0f);
        s0f += (float)ff[10].x;
        _Float16 s = (_Float16)s0f;
        hsb[t] = s;                           // c = 0
        // slide: fp16 running chain, extracts fold into op_sel
        #pragma unroll
        for (int k = 1; k < 32; ++k) {
            int ja = 20 + k, jb = k - 1;
            _Float16 fa = (ja & 1) ? ff[ja >> 1].y : ff[ja >> 1].x;
            _Float16 fb = (jb & 1) ? ff[jb >> 1].y : ff[jb >> 1].x;
            s += (_Float16)(fa - fb);
            hsb[k * RSTR + t] = s;
        }
    };

    auto do_v = [&](int du, int dv, int buf) {
        const half2_t* col = (const half2_t*)&hsAB[buf][pb][s4];  // even -> 4B aligned

        half2_t v[12];
        #pragma unroll
        for (int i = 0; i < 12; ++i) v[i] = col[i];
        float vs = 0.f;
        #pragma unroll
        for (int i = 0; i < 10; ++i) vs = FDOT2(v[i], one, vs);
        vs += (float)v[10].x;

        float vss[4];
        vss[0] = vs;
        vss[1] = vss[0] + (float)(_Float16)(v[10].y - v[0].x);
        vss[2] = vss[1] + (float)(_Float16)(v[11].x - v[0].y);
        vss[3] = vss[2] + (float)(_Float16)(v[11].y - v[1].x);

        const int cr = 10 + du;
        const int cc = pb + 10 + dv;
        #pragma unroll
        for (int k = 0; k < 4; ++k) {
            float dist = sqrtf(fmaxf(vss[k], 0.f));
            float w = __expf(dist * negI);
            half4 c = *(const half4*)&Creg4[s4 + k + cr][cc][0];
            aW[k] += w;
            aR[k] += w * (float)c.x;
            aG[k] += w * (float)c.y;
            aB[k] += w * (float)c.z;
        }
    };

    int duA = -10, dvA = (int)blockIdx.y - 10;

    for (int oA = (int)blockIdx.y; oA < NOFF; oA += 2 * NG) {
        int duB = duA, dvB = dvA + NG;
        if (dvB > 10) { dvB -= 21; duB += 1; }
        const bool hasB = (oA + NG) < NOFF;

        __syncthreads();   // hs buffers free (prev round's v done)

        if (hactive && (hasB || hw == 0))
            do_h(hw ? duB : duA, hw ? dvB : dvA, hw);

        __syncthreads();   // hs visible

        do_v(duA, dvA, 0);
        if (hasB) do_v(duB, dvB, 1);

        // advance A by 32 offsets (two wraps of 16)
        duA = duB; dvA = dvB + NG;
        if (dvA > 10) { dvA -= 21; duA += 1; }
    }

    // ---- epilogue: one float4 per pixel ----
    #pragma unroll
    for (int k = 0; k < 4; ++k) {
        int gpix = (ti + s4 + k) * IMG + (tj + pb);
        float4 st = make_float4(aR[k], aG[k], aB[k], aW[k]);
        if (DIRECT) {
            partials[(size_t)blockIdx.y * NPIX + gpix] = st;
        } else {
            float* p = (float*)&partials[gpix];
            atomicAdd(p + 0, st.x);
            atomicAdd(p + 1, st.y);
            atomicAdd(p + 2, st.z);
            atomicAdd(p + 3, st.w);
        }
    }
}

template <int NGT>
__global__ __launch_bounds__(256)
void nlm_finalize(const float4* __restrict__ partials, float* __restrict__ out)
{
    int idx = blockIdx.x * blockDim.x + threadIdx.x;
    float r = 0.f, g = 0.f, b = 0.f, w = 0.f;
    #pragma unroll
    for (int gg = 0; gg < NGT; ++gg) {
        float4 p = partials[(size_t)gg * NPIX + idx];
        r += p.x; g += p.y; b += p.z; w += p.w;
    }
    float inv = 1.0f / w;   // sum(w) >= 1 (self offset contributes exp(0))
    out[idx]            = fminf(fmaxf(r * inv, 0.f), 1.f);
    out[NPIX + idx]     = fminf(fmaxf(g * inv, 0.f), 1.f);
    out[2 * NPIX + idx] = fminf(fmaxf(b * inv, 0.f), 1.f);
}

extern "C" void kernel_launch(void* const* d_in, const int* in_sizes, int n_in,
                              void* d_out, int out_size, void* d_ws, size_t ws_size,
                              hipStream_t stream) {
    (void)in_sizes; (void)n_in; (void)out_size;
    const float* rgb  = (const float*)d_in[0];
    const float* hptr = (const float*)d_in[1];
    float* out = (float*)d_out;
    float4* partials = (float4*)d_ws;

    const bool direct = ws_size >= (size_t)NG * NPIX * sizeof(float4);  // 16.8 MB
    dim3 grid(64, NG);
    if (direct) {
        nlm_main<true><<<grid, 256, 0, stream>>>(rgb, hptr, partials);
        nlm_finalize<NG><<<NPIX / 256, 256, 0, stream>>>(partials, out);
    } else {
        (void)hipMemsetAsync(partials, 0, (size_t)NPIX * sizeof(float4), stream);
        nlm_main<false><<<grid, 256, 0, stream>>>(rgb, hptr, partials);
        nlm_finalize<1><<<NPIX / 256, 256, 0, stream>>>(partials, out);
    }
}